// Round 1
// baseline (580.845 us; speedup 1.0000x reference)
//
#include <hip/hip_runtime.h>
#include <hip/hip_bf16.h>

#define N_NODES 100000
#define N_EDGES 800000
#define D 64

// embeds[node][d] = node_emb[nodes[node]][d] + sum_f features[node][f]*feat_W[d][f] + feat_b[d]
__global__ void init_embeds_kernel(const int* __restrict__ nodes,
                                   const float* __restrict__ features,
                                   const float* __restrict__ node_emb,
                                   const float* __restrict__ feat_W,
                                   const float* __restrict__ feat_b,
                                   float* __restrict__ embeds) {
    int tid = blockIdx.x * blockDim.x + threadIdx.x;
    if (tid >= N_NODES * D) return;
    int node = tid >> 6;
    int d = tid & 63;
    float acc = feat_b[d];
    const float* f = features + (size_t)node * 10;
    const float* w = feat_W + (size_t)d * 10;
#pragma unroll
    for (int j = 0; j < 10; ++j) acc += f[j] * w[j];
    embeds[tid] = node_emb[(size_t)nodes[node] * D + d] + acc;
}

// One wave (64 lanes) per edge: lane d does agg[dst][d] += embeds[src][d]
__global__ void scatter_add_kernel(const int* __restrict__ edges,
                                   const float* __restrict__ embeds,
                                   float* __restrict__ agg) {
    int tid = blockIdx.x * blockDim.x + threadIdx.x;
    int edge = tid >> 6;
    int lane = tid & 63;
    if (edge >= N_EDGES) return;
    int src = edges[2 * edge + 0];
    int dst = edges[2 * edge + 1];
    float v = embeds[(size_t)src * D + lane];
    atomicAdd(&agg[(size_t)dst * D + lane], v);
}

// embeds = relu((embeds + agg) @ W^T + b), in place. W is [64][64] row-major (out_d, k).
__global__ void conv_update_kernel(const float* __restrict__ agg,
                                   const float* __restrict__ W,
                                   const float* __restrict__ b,
                                   float* __restrict__ embeds) {
    __shared__ float Ws[D * 65];   // +1 pad: bank = (d + k) % 32, conflict-free
    __shared__ float xs[4][D];

    for (int i = threadIdx.x; i < D * D; i += blockDim.x) {
        int d = i >> 6, k = i & 63;
        Ws[d * 65 + k] = W[i];
    }
    __syncthreads();

    int lane_d = threadIdx.x & 63;   // output dim
    int local_n = threadIdx.x >> 6;  // 0..3 node within chunk
    float bias = b[lane_d];

    const int n_chunks = (N_NODES + 3) / 4;
    for (int chunk = blockIdx.x; chunk < n_chunks; chunk += gridDim.x) {
        int node = chunk * 4 + local_n;
        if (node < N_NODES) {
            size_t base = (size_t)node * D + lane_d;
            xs[local_n][lane_d] = embeds[base] + agg[base];
        }
        __syncthreads();
        if (node < N_NODES) {
            float acc = bias;
#pragma unroll
            for (int k = 0; k < D; ++k)
                acc += xs[local_n][k] * Ws[lane_d * 65 + k];
            embeds[(size_t)node * D + lane_d] = fmaxf(acc, 0.0f);
        }
        __syncthreads();
    }
}

// out[node] = dot(embeds[node], p) / (max(||embeds[node]||,eps) * max(||p||,eps))
__global__ void final_score_kernel(const float* __restrict__ embeds,
                                   const float* __restrict__ pattern_emb,
                                   const int* __restrict__ pattern_id,
                                   float* __restrict__ out) {
    int lane = threadIdx.x & 63;
    int wave = threadIdx.x >> 6;                      // 0..3
    int node = blockIdx.x * 4 + wave;
    int pid = pattern_id[0];
    float p = pattern_emb[(size_t)pid * D + lane];

    float pn = p * p;
#pragma unroll
    for (int m = 32; m > 0; m >>= 1) pn += __shfl_xor(pn, m, 64);

    if (node < N_NODES) {
        float e = embeds[(size_t)node * D + lane];
        float dot = e * p;
        float n2 = e * e;
#pragma unroll
        for (int m = 32; m > 0; m >>= 1) {
            dot += __shfl_xor(dot, m, 64);
            n2  += __shfl_xor(n2, m, 64);
        }
        if (lane == 0) {
            float denom = fmaxf(sqrtf(n2), 1e-8f) * fmaxf(sqrtf(pn), 1e-8f);
            out[node] = dot / denom;
        }
    }
}

extern "C" void kernel_launch(void* const* d_in, const int* in_sizes, int n_in,
                              void* d_out, int out_size, void* d_ws, size_t ws_size,
                              hipStream_t stream) {
    const int*   nodes       = (const int*)d_in[0];
    const int*   edges       = (const int*)d_in[1];
    const float* features    = (const float*)d_in[2];
    const float* node_emb    = (const float*)d_in[3];
    const float* feat_W      = (const float*)d_in[4];
    const float* feat_b      = (const float*)d_in[5];
    const float* conv1_W     = (const float*)d_in[6];
    const float* conv1_b     = (const float*)d_in[7];
    const float* pattern_emb = (const float*)d_in[8];
    const int*   pattern_id  = (const int*)d_in[9];
    float* out = (float*)d_out;

    size_t emb_bytes = (size_t)N_NODES * D * sizeof(float);          // 25.6 MB
    float* embeds = (float*)d_ws;
    float* agg    = (float*)((char*)d_ws + ((emb_bytes + 255) & ~(size_t)255));

    // 1) init embeds
    {
        int total = N_NODES * D;
        init_embeds_kernel<<<(total + 255) / 256, 256, 0, stream>>>(
            nodes, features, node_emb, feat_W, feat_b, embeds);
    }

    // 2) two conv iterations
    for (int it = 0; it < 2; ++it) {
        hipMemsetAsync(agg, 0, emb_bytes, stream);
        {
            long long total = (long long)N_EDGES * 64;
            scatter_add_kernel<<<(int)((total + 255) / 256), 256, 0, stream>>>(
                edges, embeds, agg);
        }
        conv_update_kernel<<<2048, 256, 0, stream>>>(agg, conv1_W, conv1_b, embeds);
    }

    // 3) cosine similarity vs pattern
    final_score_kernel<<<(N_NODES + 3) / 4, 256, 0, stream>>>(
        embeds, pattern_emb, pattern_id, out);
}